// Round 1
// baseline (1513.231 us; speedup 1.0000x reference)
//
#include <hip/hip_runtime.h>
#include <hip/hip_bf16.h>
#include <float.h>

#define B_ROWS 32768
#define C_CODES 4096
#define D_DIM 128
#define NCHUNK 16
#define CHUNK (C_CODES / NCHUNK)   // 256 codes per block
#define TILE 32                    // codes per LDS tile (16 KB)
#define BLOCK 256

// ---------------- Kernel A: csq_half[c] = 0.5 * sum(codes[c,:]^2) ----------------
__global__ void csq_kernel(const float* __restrict__ codes, float* __restrict__ csqh) {
    const int wave = threadIdx.x >> 6;
    const int lane = threadIdx.x & 63;
    const int row = blockIdx.x * 4 + wave;          // 4096 rows, grid 1024
    const float2 v = ((const float2*)(codes + (size_t)row * D_DIM))[lane];
    float s = v.x * v.x + v.y * v.y;
    #pragma unroll
    for (int off = 32; off; off >>= 1) s += __shfl_xor(s, off);
    if (lane == 0) csqh[row] = 0.5f * s;
}

// ---------------- Kernel B: fused GEMM + partial argmax ----------------
// Each thread owns one x row (128 floats in VGPRs). Codes tile staged in LDS,
// read with wave-uniform addresses (broadcast, bank-conflict-free).
// score = x.c - 0.5*||c||^2 ; argmin distance == argmax score.
__global__ __launch_bounds__(BLOCK, 3)
void vq_argmax_kernel(const float* __restrict__ x, const float* __restrict__ codes,
                      const float* __restrict__ csqh,
                      float* __restrict__ pval, int* __restrict__ pidx) {
    __shared__ float lds[TILE * D_DIM];             // 16 KB
    const int tid = threadIdx.x;
    const int row = blockIdx.x * BLOCK + tid;
    const int cbase = blockIdx.y * CHUNK;

    float4 xr[32];
    {
        const float4* xp = (const float4*)(x + (size_t)row * D_DIM);
        #pragma unroll
        for (int i = 0; i < 32; ++i) xr[i] = xp[i];
    }

    float best = -FLT_MAX;
    int bidx = 0;

    for (int t = 0; t < CHUNK / TILE; ++t) {
        const float4* src = (const float4*)(codes + (size_t)(cbase + t * TILE) * D_DIM);
        float4* dst = (float4*)lds;
        __syncthreads();                            // previous tile compute done
        #pragma unroll
        for (int j = 0; j < 4; ++j) dst[j * BLOCK + tid] = src[j * BLOCK + tid];
        __syncthreads();                            // tile ready

        const float4* cl = (const float4*)lds;
        for (int n = 0; n < TILE; n += 4) {
            const float4* c0 = cl + (n + 0) * 32;
            const float4* c1 = cl + (n + 1) * 32;
            const float4* c2 = cl + (n + 2) * 32;
            const float4* c3 = cl + (n + 3) * 32;
            // two partial accumulators per code (shorter dep chains, lower fp error)
            float a0e = 0.f, a1e = 0.f, a2e = 0.f, a3e = 0.f;
            float a0o = 0.f, a1o = 0.f, a2o = 0.f, a3o = 0.f;
            #pragma unroll
            for (int k = 0; k < 32; ++k) {
                const float4 xv = xr[k];
                const float4 p0 = c0[k], p1 = c1[k], p2 = c2[k], p3 = c3[k];
                a0e = fmaf(xv.x, p0.x, a0e); a1e = fmaf(xv.x, p1.x, a1e);
                a2e = fmaf(xv.x, p2.x, a2e); a3e = fmaf(xv.x, p3.x, a3e);
                a0e = fmaf(xv.y, p0.y, a0e); a1e = fmaf(xv.y, p1.y, a1e);
                a2e = fmaf(xv.y, p2.y, a2e); a3e = fmaf(xv.y, p3.y, a3e);
                a0o = fmaf(xv.z, p0.z, a0o); a1o = fmaf(xv.z, p1.z, a1o);
                a2o = fmaf(xv.z, p2.z, a2o); a3o = fmaf(xv.z, p3.z, a3o);
                a0o = fmaf(xv.w, p0.w, a0o); a1o = fmaf(xv.w, p1.w, a1o);
                a2o = fmaf(xv.w, p2.w, a2o); a3o = fmaf(xv.w, p3.w, a3o);
            }
            const int cidx = cbase + t * TILE + n;
            const float s0 = (a0e + a0o) - csqh[cidx + 0];
            const float s1 = (a1e + a1o) - csqh[cidx + 1];
            const float s2 = (a2e + a2o) - csqh[cidx + 2];
            const float s3 = (a3e + a3o) - csqh[cidx + 3];
            if (s0 > best) { best = s0; bidx = cidx + 0; }
            if (s1 > best) { best = s1; bidx = cidx + 1; }
            if (s2 > best) { best = s2; bidx = cidx + 2; }
            if (s3 > best) { best = s3; bidx = cidx + 3; }
        }
    }
    pval[(size_t)blockIdx.y * B_ROWS + row] = best;
    pidx[(size_t)blockIdx.y * B_ROWS + row] = bidx;
}

// ---------------- Kernel C: reduce partials, gather, write outputs ----------------
__global__ void finalize_kernel(const float* __restrict__ x, const float* __restrict__ codes,
                                const float* __restrict__ pval, const int* __restrict__ pidx,
                                float* __restrict__ qout, float* __restrict__ idxout,
                                float* __restrict__ loss) {
    const int wave = threadIdx.x >> 6;
    const int lane = threadIdx.x & 63;
    const int row = blockIdx.x * 4 + wave;

    float v = -FLT_MAX;
    int bi = 0x7fffffff;
    if (lane < NCHUNK) {
        v = pval[(size_t)lane * B_ROWS + row];
        bi = pidx[(size_t)lane * B_ROWS + row];
    }
    // argmax over 16 lanes, ties -> smaller index (matches argmin-first semantics)
    #pragma unroll
    for (int off = 8; off; off >>= 1) {
        const float ov = __shfl_xor(v, off);
        const int oi = __shfl_xor(bi, off);
        if (ov > v || (ov == v && oi < bi)) { v = ov; bi = oi; }
    }
    bi = __shfl(bi, 0);

    const float2 xv = ((const float2*)(x + (size_t)row * D_DIM))[lane];
    const float2 qv = ((const float2*)(codes + (size_t)bi * D_DIM))[lane];
    ((float2*)(qout + (size_t)row * D_DIM))[lane] = qv;   // x + (q - x) == q numerically

    const float dx = xv.x - qv.x, dy = xv.y - qv.y;
    float s = dx * dx + dy * dy;
    #pragma unroll
    for (int off = 32; off; off >>= 1) s += __shfl_xor(s, off);
    if (lane == 0) {
        idxout[row] = (float)bi;
        // loss = loss_commit + 0.25*loss_codebook = 1.25 * mean(sum((x-q)^2))
        atomicAdd(loss, s * (1.25f / (float)B_ROWS));
    }
}

extern "C" void kernel_launch(void* const* d_in, const int* in_sizes, int n_in,
                              void* d_out, int out_size, void* d_ws, size_t ws_size,
                              hipStream_t stream) {
    const float* x = (const float*)d_in[0];
    const float* codes = (const float*)d_in[1];

    float* out = (float*)d_out;
    float* qout = out;
    float* idxout = out + (size_t)B_ROWS * D_DIM;
    float* loss = out + (size_t)B_ROWS * D_DIM + B_ROWS;

    // workspace layout
    float* pval = (float*)d_ws;                                              // 16*32768 floats
    int* pidx = (int*)((char*)d_ws + (size_t)NCHUNK * B_ROWS * 4);           // 16*32768 ints
    float* csqh = (float*)((char*)d_ws + (size_t)NCHUNK * B_ROWS * 8);       // 4096 floats

    hipMemsetAsync(loss, 0, sizeof(float), stream);
    csq_kernel<<<C_CODES / 4, 256, 0, stream>>>(codes, csqh);
    vq_argmax_kernel<<<dim3(B_ROWS / BLOCK, NCHUNK), BLOCK, 0, stream>>>(x, codes, csqh, pval, pidx);
    finalize_kernel<<<B_ROWS / 4, 256, 0, stream>>>(x, codes, pval, pidx, qout, idxout, loss);
}

// Round 2
// 379.567 us; speedup vs baseline: 3.9867x; 3.9867x over previous
//
#include <hip/hip_runtime.h>
#include <float.h>

#define B_ROWS 32768
#define C_CODES 4096
#define DDIM 128
#define MB 128            // x-rows per gemm block
#define NCHUNKS 2         // code chunks (grid.y)
#define CCHUNK 2048
#define CTILE 64          // codes per LDS tile
#define NTILES 32         // CCHUNK / CTILE
#define ROWB 256          // bytes per bf16 row

typedef __attribute__((ext_vector_type(8))) short short8;
typedef __attribute__((ext_vector_type(16))) float f32x16;
typedef unsigned int u32;
typedef unsigned short u16;

__device__ __forceinline__ u16 f2bf(float f) {
    u32 u = __float_as_uint(f);
    return (u16)((u + 0x7FFFu + ((u >> 16) & 1u)) >> 16);
}

__device__ __forceinline__ void gl2lds16(const void* g, void* l) {
    __builtin_amdgcn_global_load_lds(
        (const __attribute__((address_space(1))) u32*)g,
        (__attribute__((address_space(3))) u32*)l, 16, 0, 0);
}

// ---------------- prep: codes -> bf16 swizzled Bbig + exact fp32 csqh ----------------
__global__ void prep_codes(const float* __restrict__ codes, u16* __restrict__ Bbig,
                           float* __restrict__ csqh) {
    const int w = threadIdx.x >> 6, lane = threadIdx.x & 63;
    const int c = blockIdx.x * 4 + w;
    const float2 v = ((const float2*)(codes + (size_t)c * DDIM))[lane];
    ushort2 b; b.x = f2bf(v.x); b.y = f2bf(v.y);
    const int sw = (c & 15) << 4;
    *(ushort2*)((char*)Bbig + (size_t)c * ROWB + ((lane * 4) ^ sw)) = b;
    float s = v.x * v.x + v.y * v.y;
    #pragma unroll
    for (int off = 32; off; off >>= 1) s += __shfl_xor(s, off);
    if (lane == 0) csqh[c] = 0.5f * s;
}

// ---------------- fused bf16 MFMA GEMM + per-row top2 ----------------
// score = x.c - 0.5||c||^2 ; argmax score == argmin dist. Wave: 32 rows x 64 codes.
__global__ __launch_bounds__(256, 2)
void gemm_top2(const float* __restrict__ x, const u16* __restrict__ Bbig,
               const float* __restrict__ csqh,
               float* __restrict__ pb1, float* __restrict__ pb2,
               int* __restrict__ pi1, float* __restrict__ xsq_ws) {
    __shared__ char smem[2 * 16384 + 32768 + 1024];  // B dbuf | A (bf16 swz) | xsq partials
    char* const Areg = smem + 32768;
    float* const xsqArr = (float*)(smem + 65536);

    const int tid = threadIdx.x;
    const int lane = tid & 63;
    const int w = tid >> 6;
    const int blkrow = blockIdx.x * MB;
    const int cbase = blockIdx.y * CCHUNK;

    // ---- convert this block's 128 x-rows to bf16, swizzled, into LDS; xsq partials ----
    {
        const int r = tid >> 1, h = tid & 1;
        const float4* xp = (const float4*)(x + (size_t)(blkrow + r) * DDIM + h * 64);
        char* Arow = Areg + r * ROWB;
        const int sw = (r & 15) << 4;
        float ss = 0.f;
        #pragma unroll
        for (int i = 0; i < 16; ++i) {
            const float4 v = xp[i];
            ss += v.x * v.x + v.y * v.y + v.z * v.z + v.w * v.w;
            uint2 pk;
            pk.x = (u32)f2bf(v.x) | ((u32)f2bf(v.y) << 16);
            pk.y = (u32)f2bf(v.z) | ((u32)f2bf(v.w) << 16);
            *(uint2*)(Arow + ((h * 128 + i * 8) ^ sw)) = pk;
        }
        xsqArr[tid] = ss;
    }
    // stage B tile 0
    {
        const char* src = (const char*)Bbig + (size_t)cbase * ROWB;
        #pragma unroll
        for (int r = 0; r < 4; ++r)
            gl2lds16(src + r * 4096 + w * 1024 + lane * 16, smem + r * 4096 + w * 1024);
    }
    __syncthreads();

    // ---- load A fragments (8 ksteps) into registers ----
    const int col0 = lane & 31;
    const int khalf = (lane >> 5) << 4;        // 0 or 16 bytes (k-half)
    short8 afr[8];
    {
        const int arow = w * 32 + col0;
        const char* Ab = Areg + arow * ROWB;
        const int swa = (arow & 15) << 4;
        #pragma unroll
        for (int ks = 0; ks < 8; ++ks)
            afr[ks] = *(const short8*)(Ab + ((ks * 32 + khalf) ^ swa));
    }

    float b1v[16], b2v[16]; int b1i[16];
    #pragma unroll
    for (int r = 0; r < 16; ++r) { b1v[r] = -FLT_MAX; b2v[r] = -FLT_MAX; b1i[r] = 0; }

    const int swb = (col0 & 15) << 4;

    for (int t = 0; t < NTILES; ++t) {
        if (t + 1 < NTILES) {
            char* dbuf = smem + ((t + 1) & 1) * 16384;
            const char* src = (const char*)Bbig + (size_t)(cbase + (t + 1) * CTILE) * ROWB;
            #pragma unroll
            for (int r = 0; r < 4; ++r)
                gl2lds16(src + r * 4096 + w * 1024 + lane * 16, dbuf + r * 4096 + w * 1024);
        }
        const char* Bl = smem + (t & 1) * 16384 + col0 * ROWB;

        f32x16 acc0, acc1;
        #pragma unroll
        for (int i = 0; i < 16; ++i) { acc0[i] = 0.f; acc1[i] = 0.f; }
        #pragma unroll
        for (int ks = 0; ks < 8; ++ks) {
            const int z = (ks * 32 + khalf) ^ swb;
            const short8 bf0 = *(const short8*)(Bl + z);
            const short8 bf1 = *(const short8*)(Bl + 8192 + z);
            acc0 = __builtin_amdgcn_mfma_f32_32x32x16_bf16(afr[ks], bf0, acc0, 0, 0, 0);
            acc1 = __builtin_amdgcn_mfma_f32_32x32x16_bf16(afr[ks], bf1, acc1, 0, 0, 0);
        }
        const int ct = cbase + t * CTILE;
        const float cs0 = csqh[ct + col0];
        const float cs1 = csqh[ct + 32 + col0];
        #pragma unroll
        for (int r = 0; r < 16; ++r) {
            const float s0 = acc0[r] - cs0;
            const float s1 = acc1[r] - cs1;
            if (s0 > b1v[r]) { b2v[r] = b1v[r]; b1v[r] = s0; b1i[r] = ct + col0; }
            else if (s0 > b2v[r]) b2v[r] = s0;
            if (s1 > b1v[r]) { b2v[r] = b1v[r]; b1v[r] = s1; b1i[r] = ct + 32 + col0; }
            else if (s1 > b2v[r]) b2v[r] = s1;
        }
        __syncthreads();
    }

    // ---- merge across the 32 lanes of each half (disjoint code sets, same rows) ----
    #pragma unroll
    for (int off = 1; off <= 16; off <<= 1) {
        #pragma unroll
        for (int r = 0; r < 16; ++r) {
            const float o1 = __shfl_xor(b1v[r], off);
            const int   oi = __shfl_xor(b1i[r], off);
            const float o2 = __shfl_xor(b2v[r], off);
            const float lo = fminf(b1v[r], o1);
            const float nb2 = fmaxf(lo, fmaxf(b2v[r], o2));
            const bool take = (o1 > b1v[r]) || (o1 == b1v[r] && oi < b1i[r]);
            if (take) { b1v[r] = o1; b1i[r] = oi; }
            b2v[r] = nb2;
        }
    }
    if (col0 == 0) {
        const int hi = lane >> 5;
        #pragma unroll
        for (int r = 0; r < 16; ++r) {
            const int rloc = w * 32 + (r & 3) + 8 * (r >> 2) + 4 * hi;
            const int grow = blkrow + rloc;
            const size_t o = (size_t)blockIdx.y * B_ROWS + grow;
            pb1[o] = b1v[r]; pb2[o] = b2v[r]; pi1[o] = b1i[r];
            if (blockIdx.y == 0)
                xsq_ws[grow] = xsqArr[2 * rloc] + xsqArr[2 * rloc + 1];
        }
    }
}

// ---------------- merge 2 chunks, decide flags, compact flagged rows ----------------
__global__ void select_flag(const float* __restrict__ pb1, const float* __restrict__ pb2,
                            const int* __restrict__ pi1, const float* __restrict__ xsq_ws,
                            int* __restrict__ idxf, int* __restrict__ list, int* __restrict__ cnt) {
    const int r = blockIdx.x * 256 + threadIdx.x;
    const float a1 = pb1[r], a2 = pb2[r]; const int ai = pi1[r];
    const float o1 = pb1[B_ROWS + r], o2 = pb2[B_ROWS + r]; const int oi = pi1[B_ROWS + r];
    const float lo = fminf(a1, o1);
    const float nb2 = fmaxf(lo, fmaxf(a2, o2));
    const bool take = (o1 > a1) || (o1 == a1 && oi < ai);
    const float b1 = take ? o1 : a1;
    const int bi = take ? oi : ai;
    idxf[r] = bi;
    const float margin = 0.016f * sqrtf(xsq_ws[r]) + 0.002f;
    const bool flag = (b1 - nb2) < margin;
    const unsigned long long m = __ballot(flag);
    const int lane = threadIdx.x & 63;
    int base = 0;
    const int nw = __popcll(m);
    if (lane == 0 && nw) base = atomicAdd(cnt, nw);
    base = __shfl(base, 0);
    if (flag) {
        const int pos = base + (int)__popcll(m & ((1ull << lane) - 1ull));
        list[pos] = r;
    }
}

// ---------------- exact fp32 re-resolve for flagged rows (8 rows / block) ----------------
#define RCB 8
__global__ __launch_bounds__(256)
void recheck(const float* __restrict__ x, const float* __restrict__ codes,
             const float* __restrict__ csqh, const int* __restrict__ list,
             const int* __restrict__ cnt, int* __restrict__ idxf) {
    __shared__ float xls[RCB][DDIM];
    __shared__ float rv[256];
    __shared__ int ri[256];
    const int tid = threadIdx.x;
    const int n = *cnt;
    for (int base = blockIdx.x * RCB; base < n; base += gridDim.x * RCB) {
        const int nr = min(RCB, n - base);
        __syncthreads();
        for (int i = tid; i < nr * DDIM; i += 256) {
            const int rr = i >> 7;
            xls[rr][i & 127] = x[(size_t)list[base + rr] * DDIM + (i & 127)];
        }
        __syncthreads();
        float bv[RCB]; int bix[RCB];
        #pragma unroll
        for (int r = 0; r < RCB; ++r) { bv[r] = -FLT_MAX; bix[r] = 0; }
        for (int g = 0; g < 16; ++g) {
            const int c = g * 256 + tid;
            const float4* cp = (const float4*)(codes + (size_t)c * DDIM);
            float4 acc[RCB];
            #pragma unroll
            for (int r = 0; r < RCB; ++r) { acc[r].x = 0; acc[r].y = 0; acc[r].z = 0; acc[r].w = 0; }
            for (int k = 0; k < 32; ++k) {
                const float4 cv = cp[k];
                #pragma unroll
                for (int r = 0; r < RCB; ++r) {
                    const float4 xv = ((const float4*)xls[r])[k];
                    acc[r].x = fmaf(cv.x, xv.x, acc[r].x);
                    acc[r].y = fmaf(cv.y, xv.y, acc[r].y);
                    acc[r].z = fmaf(cv.z, xv.z, acc[r].z);
                    acc[r].w = fmaf(cv.w, xv.w, acc[r].w);
                }
            }
            const float cq = csqh[c];
            #pragma unroll
            for (int r = 0; r < RCB; ++r) {
                const float s = (acc[r].x + acc[r].y) + (acc[r].z + acc[r].w) - cq;
                if (s > bv[r]) { bv[r] = s; bix[r] = c; }
            }
        }
        for (int r = 0; r < nr; ++r) {
            rv[tid] = bv[r]; ri[tid] = bix[r];
            __syncthreads();
            for (int s2 = 128; s2; s2 >>= 1) {
                if (tid < s2) {
                    const float ov = rv[tid + s2]; const int oi2 = ri[tid + s2];
                    if (ov > rv[tid] || (ov == rv[tid] && oi2 < ri[tid])) { rv[tid] = ov; ri[tid] = oi2; }
                }
                __syncthreads();
            }
            if (tid == 0) idxf[list[base + r]] = ri[0];
            __syncthreads();
        }
    }
}

// ---------------- gather + outputs + per-block loss partials ----------------
__global__ void finalize(const float* __restrict__ x, const float* __restrict__ codes,
                         const int* __restrict__ idxf, float* __restrict__ qout,
                         float* __restrict__ idxout, float* __restrict__ partials) {
    __shared__ float ls[4];
    const int w = threadIdx.x >> 6, lane = threadIdx.x & 63;
    const int rb = blockIdx.x * 16 + w * 4;
    float wsum = 0.f;
    #pragma unroll
    for (int j = 0; j < 4; ++j) {
        const int r = rb + j;
        const int bi = idxf[r];
        const float2 xv = ((const float2*)(x + (size_t)r * DDIM))[lane];
        const float2 cv = ((const float2*)(codes + (size_t)bi * DDIM))[lane];
        ((float2*)(qout + (size_t)r * DDIM))[lane] = cv;
        if (lane == 0) idxout[r] = (float)bi;
        const float dx = xv.x - cv.x, dy = xv.y - cv.y;
        wsum += dx * dx + dy * dy;
    }
    #pragma unroll
    for (int off = 32; off; off >>= 1) wsum += __shfl_xor(wsum, off);
    if (lane == 0) ls[w] = wsum;
    __syncthreads();
    if (threadIdx.x == 0) partials[blockIdx.x] = (ls[0] + ls[1]) + (ls[2] + ls[3]);
}

__global__ void loss_reduce(const float* __restrict__ partials, float* __restrict__ loss) {
    __shared__ float ls[4];
    const int tid = threadIdx.x, w = tid >> 6, lane = tid & 63;
    float s = 0.f;
    for (int i = tid; i < 2048; i += 256) s += partials[i];
    #pragma unroll
    for (int off = 32; off; off >>= 1) s += __shfl_xor(s, off);
    if (lane == 0) ls[w] = s;
    __syncthreads();
    if (tid == 0) *loss = ((ls[0] + ls[1]) + (ls[2] + ls[3])) * (1.25f / (float)B_ROWS);
}

extern "C" void kernel_launch(void* const* d_in, const int* in_sizes, int n_in,
                              void* d_out, int out_size, void* d_ws, size_t ws_size,
                              hipStream_t stream) {
    const float* x = (const float*)d_in[0];
    const float* codes = (const float*)d_in[1];

    float* out = (float*)d_out;
    float* qout = out;
    float* idxout = out + (size_t)B_ROWS * DDIM;
    float* loss = idxout + B_ROWS;

    char* ws = (char*)d_ws;
    u16* Bbig     = (u16*)ws;                          // 1 MB
    float* csqh   = (float*)(ws + 1048576);            // 16 KB
    float* pb1    = (float*)(ws + 1064960);            // 256 KB
    float* pb2    = (float*)(ws + 1327104);            // 256 KB
    int* pi1      = (int*)(ws + 1589248);              // 256 KB
    float* xsq_ws = (float*)(ws + 1851392);            // 128 KB
    int* idxf     = (int*)(ws + 1982464);              // 128 KB
    int* list     = (int*)(ws + 2113536);              // 128 KB
    int* cnt      = (int*)(ws + 2244608);              // 4 B
    float* partials = (float*)(ws + 2244736);          // 8 KB

    hipMemsetAsync(cnt, 0, 4, stream);
    prep_codes<<<C_CODES / 4, 256, 0, stream>>>(codes, Bbig, csqh);
    gemm_top2<<<dim3(B_ROWS / MB, NCHUNKS), 256, 0, stream>>>(x, Bbig, csqh, pb1, pb2, pi1, xsq_ws);
    select_flag<<<B_ROWS / 256, 256, 0, stream>>>(pb1, pb2, pi1, xsq_ws, idxf, list, cnt);
    recheck<<<512, 256, 0, stream>>>(x, codes, csqh, list, cnt, idxf);
    finalize<<<B_ROWS / 16, 256, 0, stream>>>(x, codes, idxf, qout, idxout, partials);
    loss_reduce<<<1, 256, 0, stream>>>(partials, loss);
}

// Round 3
// 203.701 us; speedup vs baseline: 7.4287x; 1.8634x over previous
//
#include <hip/hip_runtime.h>
#include <float.h>

#define B_ROWS 32768
#define C_CODES 4096
#define DDIM 128
#define MB 128            // x-rows per gemm block
#define NCHUNKS 2         // code chunks (grid.y)
#define CCHUNK 2048
#define CTILE 64          // codes per LDS tile
#define NTILES 32         // CCHUNK / CTILE
#define ROWB 256          // bytes per bf16 row

typedef __attribute__((ext_vector_type(8))) short short8;
typedef __attribute__((ext_vector_type(16))) float f32x16;
typedef unsigned int u32;
typedef unsigned short u16;

__device__ __forceinline__ u16 f2bf(float f) {
    u32 u = __float_as_uint(f);
    return (u16)((u + 0x7FFFu + ((u >> 16) & 1u)) >> 16);
}

__device__ __forceinline__ void gl2lds16(const void* g, void* l) {
    __builtin_amdgcn_global_load_lds(
        (const __attribute__((address_space(1))) u32*)g,
        (__attribute__((address_space(3))) u32*)l, 16, 0, 0);
}

// ---------------- prep: codes -> bf16 swizzled Bbig + exact fp32 csqh ----------------
__global__ void prep_codes(const float* __restrict__ codes, u16* __restrict__ Bbig,
                           float* __restrict__ csqh) {
    const int w = threadIdx.x >> 6, lane = threadIdx.x & 63;
    const int c = blockIdx.x * 4 + w;
    const float2 v = ((const float2*)(codes + (size_t)c * DDIM))[lane];
    ushort2 b; b.x = f2bf(v.x); b.y = f2bf(v.y);
    const int sw = (c & 15) << 4;
    *(ushort2*)((char*)Bbig + (size_t)c * ROWB + ((lane * 4) ^ sw)) = b;
    float s = v.x * v.x + v.y * v.y;
    #pragma unroll
    for (int off = 32; off; off >>= 1) s += __shfl_xor(s, off);
    if (lane == 0) csqh[c] = 0.5f * s;
}

// ---------------- fused bf16 MFMA GEMM + per-row top2 (branchless) ----------------
// score = x.c - 0.5||c||^2 ; argmax score == argmin dist.
// -0.5||c||^2 folded into accumulator init; top2 via fmed3/fmax; idx via cndmask.
__global__ __launch_bounds__(256, 2)
void gemm_top2(const float* __restrict__ x, const u16* __restrict__ Bbig,
               const float* __restrict__ csqh,
               float* __restrict__ pb1, float* __restrict__ pb2,
               int* __restrict__ pi1, float* __restrict__ xsq_ws) {
    __shared__ char smem[2 * 16384 + 32768 + 8192 + 1024];  // B dbuf | A swz | -csq | xsq
    char* const Areg = smem + 32768;
    float* const csq_l = (float*)(smem + 65536);
    float* const xsqArr = (float*)(smem + 65536 + 8192);

    const int tid = threadIdx.x;
    const int lane = tid & 63;
    const int w = tid >> 6;
    const int blkrow = blockIdx.x * MB;
    const int cbase = blockIdx.y * CCHUNK;

    // ---- stage negated csq chunk to LDS ----
    {
        const float4* cs = (const float4*)(csqh + cbase);
        #pragma unroll
        for (int j = 0; j < 2; ++j) {
            const float4 v = cs[j * 256 + tid];
            float4 n; n.x = -v.x; n.y = -v.y; n.z = -v.z; n.w = -v.w;
            ((float4*)csq_l)[j * 256 + tid] = n;
        }
    }
    // ---- convert this block's 128 x-rows to bf16, swizzled, into LDS; xsq partials ----
    {
        const int r = tid >> 1, h = tid & 1;
        const float4* xp = (const float4*)(x + (size_t)(blkrow + r) * DDIM + h * 64);
        char* Arow = Areg + r * ROWB;
        const int sw = (r & 15) << 4;
        float ss = 0.f;
        #pragma unroll
        for (int i = 0; i < 16; ++i) {
            const float4 v = xp[i];
            ss += v.x * v.x + v.y * v.y + v.z * v.z + v.w * v.w;
            uint2 pk;
            pk.x = (u32)f2bf(v.x) | ((u32)f2bf(v.y) << 16);
            pk.y = (u32)f2bf(v.z) | ((u32)f2bf(v.w) << 16);
            *(uint2*)(Arow + ((h * 128 + i * 8) ^ sw)) = pk;
        }
        xsqArr[tid] = ss;
    }
    // stage B tile 0
    {
        const char* src = (const char*)Bbig + (size_t)cbase * ROWB;
        #pragma unroll
        for (int r = 0; r < 4; ++r)
            gl2lds16(src + r * 4096 + w * 1024 + lane * 16, smem + r * 4096 + w * 1024);
    }
    __syncthreads();

    // ---- load A fragments (8 ksteps) into registers ----
    const int col0 = lane & 31;
    const int khalf = (lane >> 5) << 4;        // 0 or 16 bytes (k-half)
    short8 afr[8];
    {
        const int arow = w * 32 + col0;
        const char* Ab = Areg + arow * ROWB;
        const int swa = (arow & 15) << 4;
        #pragma unroll
        for (int ks = 0; ks < 8; ++ks)
            afr[ks] = *(const short8*)(Ab + ((ks * 32 + khalf) ^ swa));
    }

    float b1v[16], b2v[16]; int b1i[16];
    #pragma unroll
    for (int r = 0; r < 16; ++r) { b1v[r] = -FLT_MAX; b2v[r] = -FLT_MAX; b1i[r] = 0; }

    const int swb = (col0 & 15) << 4;

    for (int t = 0; t < NTILES; ++t) {
        if (t + 1 < NTILES) {
            char* dbuf = smem + ((t + 1) & 1) * 16384;
            const char* src = (const char*)Bbig + (size_t)(cbase + (t + 1) * CTILE) * ROWB;
            #pragma unroll
            for (int r = 0; r < 4; ++r)
                gl2lds16(src + r * 4096 + w * 1024 + lane * 16, dbuf + r * 4096 + w * 1024);
        }
        const char* Bl = smem + (t & 1) * 16384 + col0 * ROWB;

        const float cs0 = csq_l[t * CTILE + col0];        // already negated
        const float cs1 = csq_l[t * CTILE + 32 + col0];
        f32x16 acc0, acc1;
        #pragma unroll
        for (int i = 0; i < 16; ++i) { acc0[i] = cs0; acc1[i] = cs1; }
        #pragma unroll
        for (int ks = 0; ks < 8; ++ks) {
            const int z = (ks * 32 + khalf) ^ swb;
            const short8 bf0 = *(const short8*)(Bl + z);
            const short8 bf1 = *(const short8*)(Bl + 8192 + z);
            acc0 = __builtin_amdgcn_mfma_f32_32x32x16_bf16(afr[ks], bf0, acc0, 0, 0, 0);
            acc1 = __builtin_amdgcn_mfma_f32_32x32x16_bf16(afr[ks], bf1, acc1, 0, 0, 0);
        }
        const int idx0 = cbase + t * CTILE + col0;
        const int idx1 = idx0 + 32;
        #pragma unroll
        for (int r = 0; r < 16; ++r) {
            const float s0 = acc0[r];
            const float s1 = acc1[r];
            // branchless top-2 with index: 4 VALU per element
            const float m2a = __builtin_amdgcn_fmed3f(b1v[r], b2v[r], s0);
            const int   nia = (s0 > b1v[r]) ? idx0 : b1i[r];
            const float n1a = fmaxf(b1v[r], s0);
            b2v[r] = __builtin_amdgcn_fmed3f(n1a, m2a, s1);
            b1i[r] = (s1 > n1a) ? idx1 : nia;
            b1v[r] = fmaxf(n1a, s1);
        }
        __syncthreads();
    }

    // ---- merge across the 32 lanes of each half (disjoint code sets, same rows) ----
    #pragma unroll
    for (int off = 1; off <= 16; off <<= 1) {
        #pragma unroll
        for (int r = 0; r < 16; ++r) {
            const float o1 = __shfl_xor(b1v[r], off);
            const int   oi = __shfl_xor(b1i[r], off);
            const float o2 = __shfl_xor(b2v[r], off);
            const float lo = fminf(b1v[r], o1);
            const float nb2 = fmaxf(lo, fmaxf(b2v[r], o2));
            const bool take = (o1 > b1v[r]) || (o1 == b1v[r] && oi < b1i[r]);
            if (take) { b1v[r] = o1; b1i[r] = oi; }
            b2v[r] = nb2;
        }
    }
    if (col0 == 0) {
        const int hi = lane >> 5;
        #pragma unroll
        for (int r = 0; r < 16; ++r) {
            const int rloc = w * 32 + (r & 3) + 8 * (r >> 2) + 4 * hi;
            const int grow = blkrow + rloc;
            const size_t o = (size_t)blockIdx.y * B_ROWS + grow;
            pb1[o] = b1v[r]; pb2[o] = b2v[r]; pi1[o] = b1i[r];
            if (blockIdx.y == 0)
                xsq_ws[grow] = xsqArr[2 * rloc] + xsqArr[2 * rloc + 1];
        }
    }
}

// ---------------- merge 2 chunks, decide flags, compact flagged rows ----------------
__global__ void select_flag(const float* __restrict__ pb1, const float* __restrict__ pb2,
                            const int* __restrict__ pi1, const float* __restrict__ xsq_ws,
                            int* __restrict__ idxf, int* __restrict__ list, int* __restrict__ cnt) {
    const int r = blockIdx.x * 256 + threadIdx.x;
    const float a1 = pb1[r], a2 = pb2[r]; const int ai = pi1[r];
    const float o1 = pb1[B_ROWS + r], o2 = pb2[B_ROWS + r]; const int oi = pi1[B_ROWS + r];
    const float lo = fminf(a1, o1);
    const float nb2 = fmaxf(lo, fmaxf(a2, o2));
    const bool take = (o1 > a1) || (o1 == a1 && oi < ai);
    const float b1 = take ? o1 : a1;
    const int bi = take ? oi : ai;
    idxf[r] = bi;
    const float margin = 0.016f * sqrtf(xsq_ws[r]) + 0.002f;
    const bool flag = (b1 - nb2) < margin;
    const unsigned long long m = __ballot(flag);
    const int lane = threadIdx.x & 63;
    int base = 0;
    const int nw = __popcll(m);
    if (lane == 0 && nw) base = atomicAdd(cnt, nw);
    base = __shfl(base, 0);
    if (flag) {
        const int pos = base + (int)__popcll(m & ((1ull << lane) - 1ull));
        list[pos] = r;
    }
}

// ---------------- exact fp32 re-resolve for flagged rows (8 rows / block) ----------------
#define RCB 8
__global__ __launch_bounds__(256)
void recheck(const float* __restrict__ x, const float* __restrict__ codes,
             const float* __restrict__ csqh, const int* __restrict__ list,
             const int* __restrict__ cnt, int* __restrict__ idxf) {
    __shared__ float xls[RCB][DDIM];
    __shared__ float rv[256];
    __shared__ int ri[256];
    const int tid = threadIdx.x;
    const int n = *cnt;
    for (int base = blockIdx.x * RCB; base < n; base += gridDim.x * RCB) {
        const int nr = min(RCB, n - base);
        __syncthreads();
        for (int i = tid; i < nr * DDIM; i += 256) {
            const int rr = i >> 7;
            xls[rr][i & 127] = x[(size_t)list[base + rr] * DDIM + (i & 127)];
        }
        __syncthreads();
        float bv[RCB]; int bix[RCB];
        #pragma unroll
        for (int r = 0; r < RCB; ++r) { bv[r] = -FLT_MAX; bix[r] = 0; }
        for (int g = 0; g < 16; ++g) {
            const int c = g * 256 + tid;
            const float4* cp = (const float4*)(codes + (size_t)c * DDIM);
            float4 acc[RCB];
            #pragma unroll
            for (int r = 0; r < RCB; ++r) { acc[r].x = 0; acc[r].y = 0; acc[r].z = 0; acc[r].w = 0; }
            for (int k = 0; k < 32; ++k) {
                const float4 cv = cp[k];
                #pragma unroll
                for (int r = 0; r < RCB; ++r) {
                    const float4 xv = ((const float4*)xls[r])[k];
                    acc[r].x = fmaf(cv.x, xv.x, acc[r].x);
                    acc[r].y = fmaf(cv.y, xv.y, acc[r].y);
                    acc[r].z = fmaf(cv.z, xv.z, acc[r].z);
                    acc[r].w = fmaf(cv.w, xv.w, acc[r].w);
                }
            }
            const float cq = csqh[c];
            #pragma unroll
            for (int r = 0; r < RCB; ++r) {
                const float s = (acc[r].x + acc[r].y) + (acc[r].z + acc[r].w) - cq;
                if (s > bv[r]) { bv[r] = s; bix[r] = c; }
            }
        }
        for (int r = 0; r < nr; ++r) {
            rv[tid] = bv[r]; ri[tid] = bix[r];
            __syncthreads();
            for (int s2 = 128; s2; s2 >>= 1) {
                if (tid < s2) {
                    const float ov = rv[tid + s2]; const int oi2 = ri[tid + s2];
                    if (ov > rv[tid] || (ov == rv[tid] && oi2 < ri[tid])) { rv[tid] = ov; ri[tid] = oi2; }
                }
                __syncthreads();
            }
            if (tid == 0) idxf[list[base + r]] = ri[0];
            __syncthreads();
        }
    }
}

// ---------------- gather + outputs + per-block loss partials ----------------
__global__ void finalize(const float* __restrict__ x, const float* __restrict__ codes,
                         const int* __restrict__ idxf, float* __restrict__ qout,
                         float* __restrict__ idxout, float* __restrict__ partials) {
    __shared__ float ls[4];
    const int w = threadIdx.x >> 6, lane = threadIdx.x & 63;
    const int rb = blockIdx.x * 16 + w * 4;
    float wsum = 0.f;
    #pragma unroll
    for (int j = 0; j < 4; ++j) {
        const int r = rb + j;
        const int bi = idxf[r];
        const float2 xv = ((const float2*)(x + (size_t)r * DDIM))[lane];
        const float2 cv = ((const float2*)(codes + (size_t)bi * DDIM))[lane];
        ((float2*)(qout + (size_t)r * DDIM))[lane] = cv;
        if (lane == 0) idxout[r] = (float)bi;
        const float dx = xv.x - cv.x, dy = xv.y - cv.y;
        wsum += dx * dx + dy * dy;
    }
    #pragma unroll
    for (int off = 32; off; off >>= 1) wsum += __shfl_xor(wsum, off);
    if (lane == 0) ls[w] = wsum;
    __syncthreads();
    if (threadIdx.x == 0) partials[blockIdx.x] = (ls[0] + ls[1]) + (ls[2] + ls[3]);
}

__global__ void loss_reduce(const float* __restrict__ partials, float* __restrict__ loss) {
    __shared__ float ls[4];
    const int tid = threadIdx.x, w = tid >> 6, lane = tid & 63;
    float s = 0.f;
    for (int i = tid; i < 2048; i += 256) s += partials[i];
    #pragma unroll
    for (int off = 32; off; off >>= 1) s += __shfl_xor(s, off);
    if (lane == 0) ls[w] = s;
    __syncthreads();
    if (tid == 0) *loss = ((ls[0] + ls[1]) + (ls[2] + ls[3])) * (1.25f / (float)B_ROWS);
}

extern "C" void kernel_launch(void* const* d_in, const int* in_sizes, int n_in,
                              void* d_out, int out_size, void* d_ws, size_t ws_size,
                              hipStream_t stream) {
    const float* x = (const float*)d_in[0];
    const float* codes = (const float*)d_in[1];

    float* out = (float*)d_out;
    float* qout = out;
    float* idxout = out + (size_t)B_ROWS * DDIM;
    float* loss = idxout + B_ROWS;

    char* ws = (char*)d_ws;
    u16* Bbig     = (u16*)ws;                          // 1 MB
    float* csqh   = (float*)(ws + 1048576);            // 16 KB
    float* pb1    = (float*)(ws + 1064960);            // 256 KB
    float* pb2    = (float*)(ws + 1327104);            // 256 KB
    int* pi1      = (int*)(ws + 1589248);              // 256 KB
    float* xsq_ws = (float*)(ws + 1851392);            // 128 KB
    int* idxf     = (int*)(ws + 1982464);              // 128 KB
    int* list     = (int*)(ws + 2113536);              // 128 KB
    int* cnt      = (int*)(ws + 2244608);              // 4 B
    float* partials = (float*)(ws + 2244736);          // 8 KB

    hipMemsetAsync(cnt, 0, 4, stream);
    prep_codes<<<C_CODES / 4, 256, 0, stream>>>(codes, Bbig, csqh);
    gemm_top2<<<dim3(B_ROWS / MB, NCHUNKS), 256, 0, stream>>>(x, Bbig, csqh, pb1, pb2, pi1, xsq_ws);
    select_flag<<<B_ROWS / 256, 256, 0, stream>>>(pb1, pb2, pi1, xsq_ws, idxf, list, cnt);
    recheck<<<512, 256, 0, stream>>>(x, codes, csqh, list, cnt, idxf);
    finalize<<<B_ROWS / 16, 256, 0, stream>>>(x, codes, idxf, qout, idxout, partials);
    loss_reduce<<<1, 256, 0, stream>>>(partials, loss);
}